// Round 3
// baseline (622.382 us; speedup 1.0000x reference)
//
#include <hip/hip_runtime.h>
#include <math.h>

#define N_ROWS 65536
#define K_CODES 4096
#define DIM 64
#define BK 128          // codes per LDS tile: 128*64*4 = 32 KB
#define K_CHUNKS 8
#define CODES_PER_CHUNK (K_CODES / K_CHUNKS)    // 512
#define R_PER_THREAD 3
#define ROWS_PER_BLOCK (256 * R_PER_THREAD)     // 768
#define ROW_GROUPS ((N_ROWS + ROWS_PER_BLOCK - 1) / ROWS_PER_BLOCK)  // 86

// ---------------------------------------------------------------------------
// Kernel A: e_sq[k] = sum_d embed[k][d]^2
// ---------------------------------------------------------------------------
__global__ __launch_bounds__(256) void esq_kernel(const float* __restrict__ embed,
                                                  float* __restrict__ esq) {
    int k = blockIdx.x * blockDim.x + threadIdx.x;
    if (k >= K_CODES) return;
    const float4* e4 = (const float4*)(embed + (size_t)k * DIM);
    float s0 = 0.f, s1 = 0.f, s2 = 0.f, s3 = 0.f;
#pragma unroll
    for (int i = 0; i < DIM / 4; ++i) {
        float4 v = e4[i];
        s0 = fmaf(v.x, v.x, s0);
        s1 = fmaf(v.y, v.y, s1);
        s2 = fmaf(v.z, v.z, s2);
        s3 = fmaf(v.w, v.w, s3);
    }
    esq[k] = (s0 + s1) + (s2 + s3);
}

// ---------------------------------------------------------------------------
// Kernel B: partial argmin over one K-chunk, 3 rows per thread.
// grid = ROW_GROUPS * K_CHUNKS; ~2 blocks/CU (VGPR-capped).
// ---------------------------------------------------------------------------
__global__ __launch_bounds__(256, 2) void vq_partial(const float* __restrict__ x,
                                                     const float* __restrict__ embed,
                                                     const float* __restrict__ esq,
                                                     float* __restrict__ keys,
                                                     int* __restrict__ idxs) {
    __shared__ float lds_e[BK * DIM];   // 32 KB
    __shared__ float lds_q[BK];

    const int kc = blockIdx.x & (K_CHUNKS - 1);
    const int rg = blockIdx.x >> 3;     // log2(K_CHUNKS)
    const int t = threadIdx.x;
    // Clamp rows in the final (partial) row group: duplicate work, identical
    // deterministic writes -> benign.
    const int rowA = min(rg * ROWS_PER_BLOCK + t,       N_ROWS - 1);
    const int rowB = min(rg * ROWS_PER_BLOCK + t + 256, N_ROWS - 1);
    const int rowC = min(rg * ROWS_PER_BLOCK + t + 512, N_ROWS - 1);
    const int kbase = kc * CODES_PER_CHUNK;

    // Three x rows in registers: 192 VGPRs.
    float xa[DIM], xb[DIM], xc[DIM];
    {
        const float4* pa = (const float4*)(x + (size_t)rowA * DIM);
        const float4* pb = (const float4*)(x + (size_t)rowB * DIM);
        const float4* pc = (const float4*)(x + (size_t)rowC * DIM);
#pragma unroll
        for (int i = 0; i < DIM / 4; ++i) {
            float4 va = pa[i], vb = pb[i], vc = pc[i];
            xa[4 * i + 0] = va.x; xa[4 * i + 1] = va.y;
            xa[4 * i + 2] = va.z; xa[4 * i + 3] = va.w;
            xb[4 * i + 0] = vb.x; xb[4 * i + 1] = vb.y;
            xb[4 * i + 2] = vb.z; xb[4 * i + 3] = vb.w;
            xc[4 * i + 0] = vc.x; xc[4 * i + 1] = vc.y;
            xc[4 * i + 2] = vc.z; xc[4 * i + 3] = vc.w;
        }
    }

    float bestA = INFINITY, bestB = INFINITY, bestC = INFINITY;
    int ia = 0, ib = 0, ic = 0;

    for (int tile = 0; tile < CODES_PER_CHUNK / BK; ++tile) {
        __syncthreads();  // protect previous tile's readers
        {
            const float4* src =
                (const float4*)(embed + (size_t)(kbase + tile * BK) * DIM);
            float4* dst = (float4*)lds_e;
#pragma unroll
            for (int i = 0; i < (BK * DIM / 4) / 256; ++i)
                dst[t + i * 256] = src[t + i * 256];
            if (t < BK / 4)
                ((float4*)lds_q)[t] =
                    ((const float4*)(esq + kbase + tile * BK))[t];
        }
        __syncthreads();

#pragma unroll 1
        for (int k = 0; k < BK; ++k) {
            const float4* ek = (const float4*)(lds_e + k * DIM);  // uniform -> broadcast
            float a0 = 0.f, a1 = 0.f, a2 = 0.f, a3 = 0.f;
            float b0 = 0.f, b1 = 0.f, b2 = 0.f, b3 = 0.f;
            float c0 = 0.f, c1 = 0.f, c2 = 0.f, c3 = 0.f;
#pragma unroll
            for (int i = 0; i < DIM / 4; ++i) {
                float4 v = ek[i];
                a0 = fmaf(xa[4 * i + 0], v.x, a0);
                a1 = fmaf(xa[4 * i + 1], v.y, a1);
                a2 = fmaf(xa[4 * i + 2], v.z, a2);
                a3 = fmaf(xa[4 * i + 3], v.w, a3);
                b0 = fmaf(xb[4 * i + 0], v.x, b0);
                b1 = fmaf(xb[4 * i + 1], v.y, b1);
                b2 = fmaf(xb[4 * i + 2], v.z, b2);
                b3 = fmaf(xb[4 * i + 3], v.w, b3);
                c0 = fmaf(xc[4 * i + 0], v.x, c0);
                c1 = fmaf(xc[4 * i + 1], v.y, c1);
                c2 = fmaf(xc[4 * i + 2], v.z, c2);
                c3 = fmaf(xc[4 * i + 3], v.w, c3);
            }
            float eq = lds_q[k];
            float ka = fmaf(-2.0f, (a0 + a1) + (a2 + a3), eq);
            float kb = fmaf(-2.0f, (b0 + b1) + (b2 + b3), eq);
            float kc2 = fmaf(-2.0f, (c0 + c1) + (c2 + c3), eq);
            int gc = kbase + tile * BK + k;
            if (ka < bestA)  { bestA = ka;  ia = gc; }
            if (kb < bestB)  { bestB = kb;  ib = gc; }
            if (kc2 < bestC) { bestC = kc2; ic = gc; }
        }
    }

    keys[(size_t)kc * N_ROWS + rowA] = bestA;
    keys[(size_t)kc * N_ROWS + rowB] = bestB;
    keys[(size_t)kc * N_ROWS + rowC] = bestC;
    idxs[(size_t)kc * N_ROWS + rowA] = ia;
    idxs[(size_t)kc * N_ROWS + rowB] = ib;
    idxs[(size_t)kc * N_ROWS + rowC] = ic;
}

// ---------------------------------------------------------------------------
// Kernel C: merge K_CHUNKS candidates per row (ascending chunk order, strict <
// == numpy first-min), write index + gather code row.
// ---------------------------------------------------------------------------
__global__ __launch_bounds__(256) void vq_merge(const float* __restrict__ embed,
                                                const float* __restrict__ keys,
                                                const int* __restrict__ idxs,
                                                float* __restrict__ out_q,
                                                float* __restrict__ out_ind) {
    int r = blockIdx.x * blockDim.x + threadIdx.x;
    if (r >= N_ROWS) return;
    float best = keys[r];
    int bi = idxs[r];
#pragma unroll
    for (int c = 1; c < K_CHUNKS; ++c) {
        float k2 = keys[(size_t)c * N_ROWS + r];
        int i2 = idxs[(size_t)c * N_ROWS + r];
        if (k2 < best) { best = k2; bi = i2; }
    }
    out_ind[r] = (float)bi;
    const float4* src = (const float4*)(embed + (size_t)bi * DIM);
    float4* dst = (float4*)(out_q + (size_t)r * DIM);
#pragma unroll
    for (int i = 0; i < DIM / 4; ++i) dst[i] = src[i];
}

// ---------------------------------------------------------------------------
extern "C" void kernel_launch(void* const* d_in, const int* in_sizes, int n_in,
                              void* d_out, int out_size, void* d_ws, size_t ws_size,
                              hipStream_t stream) {
    const float* x = (const float*)d_in[0];      // [N, D] fp32
    const float* embed = (const float*)d_in[1];  // [1, K, D] fp32
    float* out = (float*)d_out;                  // [N*D quantize][N indices]

    float* esq = (float*)d_ws;                               // K floats
    float* keys = esq + K_CODES;                             // K_CHUNKS * N floats
    int* idxs = (int*)(keys + (size_t)K_CHUNKS * N_ROWS);    // K_CHUNKS * N ints

    esq_kernel<<<K_CODES / 256, 256, 0, stream>>>(embed, esq);
    vq_partial<<<ROW_GROUPS * K_CHUNKS, 256, 0, stream>>>(x, embed, esq, keys, idxs);
    vq_merge<<<N_ROWS / 256, 256, 0, stream>>>(embed, keys, idxs, out,
                                               out + (size_t)N_ROWS * DIM);
}

// Round 4
// 172.061 us; speedup vs baseline: 3.6172x; 3.6172x over previous
//
#include <hip/hip_runtime.h>
#include <math.h>

#define N_ROWS 65536
#define K_CODES 4096
#define DIM 64
#define NTILES (K_CODES / 32)   // 128 code tiles of 32
#define MARGIN 0.01f            // flag threshold: ~50x the bf16-split error bound

typedef __attribute__((ext_vector_type(8))) short bf16x8;
typedef __attribute__((ext_vector_type(16))) float f32x16;

__device__ inline unsigned short f2bf_rne(float f) {
    unsigned u = __float_as_uint(f);
    return (unsigned short)((u + 0x7FFFu + ((u >> 16) & 1u)) >> 16);
}
__device__ inline float bf2f(unsigned short s) {
    return __uint_as_float(((unsigned)s) << 16);
}

// ---------------------------------------------------------------------------
// pack_e: e[k][d] fp32 -> hi/lo bf16 fragments packed so that lane l, elem j
// holds e[tile*32 + (l&31)][ks*16 + (l>>5)*8 + j]. Same formula used for the
// in-register x split in vq_main => MFMA k-permutation-invariant. Also e_sq
// and count=0.
// ---------------------------------------------------------------------------
__global__ __launch_bounds__(256) void pack_e(const float* __restrict__ embed,
                                              short* __restrict__ e_pk,
                                              float* __restrict__ esq,
                                              int* __restrict__ count) {
    __shared__ float lds_f[2048];   // 32 codes x 64 dims
    const int tile = blockIdx.x;
    const int t = threadIdx.x;
    if (tile == 0 && t == 0) *count = 0;
    const float4* src = (const float4*)(embed + (size_t)tile * 2048);
    ((float4*)lds_f)[t] = src[t];
    ((float4*)lds_f)[t + 256] = src[t + 256];
    __syncthreads();
    const int l = t & 63, ks = t >> 6;
    const int base = (l & 31) * 64 + ks * 16 + (l >> 5) * 8;
    bf16x8 vh, vl;
#pragma unroll
    for (int j = 0; j < 8; ++j) {
        float v = lds_f[base + j];
        unsigned short h = f2bf_rne(v);
        vh[j] = (short)h;
        vl[j] = (short)f2bf_rne(v - bf2f(h));
    }
    *(bf16x8*)(e_pk + (size_t)tile * 4096 + t * 8) = vh;
    *(bf16x8*)(e_pk + (size_t)tile * 4096 + 2048 + t * 8) = vl;
    if (t < 32) {
        float s = 0.f;
#pragma unroll
        for (int d = 0; d < 64; ++d) { float v = lds_f[t * 64 + d]; s = fmaf(v, v, s); }
        esq[tile * 32 + t] = s;
    }
}

// ---------------------------------------------------------------------------
// vq_main: wave = 32 rows, block = 4 waves = 128 rows, all 4096 codes.
// 3-term bf16-split MFMA; per-lane running (best, second, idx); shfl merge;
// rows with gap < MARGIN appended to rescore list.
// ---------------------------------------------------------------------------
__global__ __launch_bounds__(256, 2) void vq_main(const float* __restrict__ x,
                                                  const short* __restrict__ e_pk,
                                                  const float* __restrict__ esq,
                                                  int* __restrict__ idxf,
                                                  int* __restrict__ list,
                                                  int* __restrict__ count) {
    __shared__ __align__(16) char lds[2][8192];   // dbuf: [hi 4KB][lo 4KB]
    const int tid = threadIdx.x;
    const int wid = tid >> 6;
    const int l = tid & 63;
    const int col = l & 31;
    const int g = l >> 5;
    const int rowbase = blockIdx.x * 128 + wid * 32;

    // A fragments: split this lane's x row slice on the fly (same k-packing
    // formula as pack_e).
    const float* xrow = x + (size_t)(rowbase + col) * DIM;
    bf16x8 ah[4], al[4];
#pragma unroll
    for (int ks = 0; ks < 4; ++ks) {
        const float* p = xrow + ks * 16 + g * 8;
#pragma unroll
        for (int j = 0; j < 8; ++j) {
            float v = p[j];
            unsigned short h = f2bf_rne(v);
            ah[ks][j] = (short)h;
            al[ks][j] = (short)f2bf_rne(v - bf2f(h));
        }
    }

    float b1[16], b2[16];
    int i1[16];
#pragma unroll
    for (int i = 0; i < 16; ++i) { b1[i] = 3.0e38f; b2[i] = 3.0e38f; i1[i] = 0; }

    auto stage = [&](int t, int b) {
        const char* gsrc = (const char*)e_pk + (size_t)t * 8192 + tid * 16;
        __builtin_amdgcn_global_load_lds(
            (const __attribute__((address_space(1))) void*)gsrc,
            (__attribute__((address_space(3))) void*)(&lds[b][wid * 1024]), 16, 0, 0);
        __builtin_amdgcn_global_load_lds(
            (const __attribute__((address_space(1))) void*)(gsrc + 4096),
            (__attribute__((address_space(3))) void*)(&lds[b][4096 + wid * 1024]), 16, 0, 0);
    };

    stage(0, 0);
    asm volatile("s_waitcnt vmcnt(0)" ::: "memory");
    __syncthreads();

    for (int t = 0; t < NTILES; ++t) {
        const int cur = t & 1;
        if (t + 1 < NTILES) stage(t + 1, cur ^ 1);   // prefetch overlaps compute
        const float esq_v = esq[t * 32 + col];
        const int cidx = t * 32 + col;

        f32x16 acc;
#pragma unroll
        for (int i = 0; i < 16; ++i) acc[i] = 0.f;

#pragma unroll
        for (int ks = 0; ks < 4; ++ks) {
            const bf16x8 bh = *(const bf16x8*)(&lds[cur][(ks * 64 + l) * 16]);
            const bf16x8 bl = *(const bf16x8*)(&lds[cur][4096 + (ks * 64 + l) * 16]);
            acc = __builtin_amdgcn_mfma_f32_32x32x16_bf16(ah[ks], bh, acc, 0, 0, 0);
            acc = __builtin_amdgcn_mfma_f32_32x32x16_bf16(ah[ks], bl, acc, 0, 0, 0);
            acc = __builtin_amdgcn_mfma_f32_32x32x16_bf16(al[ks], bh, acc, 0, 0, 0);
        }

#pragma unroll
        for (int i = 0; i < 16; ++i) {
            float key = fmaf(-2.0f, acc[i], esq_v);
            bool lt = key < b1[i];
            float sel = lt ? b1[i] : key;
            b2[i] = fminf(b2[i], sel);
            b1[i] = lt ? key : b1[i];
            i1[i] = lt ? cidx : i1[i];
        }

        asm volatile("s_waitcnt vmcnt(0)" ::: "memory");
        __syncthreads();
    }

    // Cross-lane merge over the 32 cols (within each half-wave).
#pragma unroll
    for (int i = 0; i < 16; ++i) {
#pragma unroll
        for (int m = 1; m <= 16; m <<= 1) {
            float ob1 = __shfl_xor(b1[i], m);
            float ob2 = __shfl_xor(b2[i], m);
            int oi = __shfl_xor(i1[i], m);
            float nb2 = fminf(fmaxf(b1[i], ob1), fminf(b2[i], ob2));
            bool take = ob1 < b1[i];
            b1[i] = take ? ob1 : b1[i];
            i1[i] = take ? oi : i1[i];
            b2[i] = nb2;
        }
        if (col == 0) {
            int row = rowbase + (i & 3) + 8 * (i >> 2) + 4 * g;  // m101 C/D row map
            idxf[row] = i1[i];
            if (b2[i] - b1[i] < MARGIN) {
                int p = atomicAdd(count, 1);
                list[p] = row;
            }
        }
    }
}

// ---------------------------------------------------------------------------
// vq_rescore: exact fp32 full rescan of flagged rows (numpy first-min rule via
// lexicographic (key, idx)). One block per flagged row, grid-strided.
// ---------------------------------------------------------------------------
__global__ __launch_bounds__(256) void vq_rescore(const float* __restrict__ x,
                                                  const float* __restrict__ embed,
                                                  const float* __restrict__ esq,
                                                  int* __restrict__ idxf,
                                                  const int* __restrict__ list,
                                                  const int* __restrict__ count) {
    __shared__ float xs[64];
    __shared__ float sk[256];
    __shared__ int si[256];
    const int tid = threadIdx.x;
    const int n = *count;
    for (int f = blockIdx.x; f < n; f += gridDim.x) {
        const int row = list[f];
        if (tid < 16) ((float4*)xs)[tid] = ((const float4*)(x + (size_t)row * DIM))[tid];
        __syncthreads();
        float best = 3.0e38f;
        int bi = 0;
        for (int i = 0; i < 16; ++i) {
            int c = tid + (i << 8);
            const float* e = embed + (size_t)c * DIM;
            float d0 = 0, d1 = 0, d2 = 0, d3 = 0;
#pragma unroll
            for (int d = 0; d < 64; d += 4) {
                d0 = fmaf(xs[d + 0], e[d + 0], d0);
                d1 = fmaf(xs[d + 1], e[d + 1], d1);
                d2 = fmaf(xs[d + 2], e[d + 2], d2);
                d3 = fmaf(xs[d + 3], e[d + 3], d3);
            }
            float key = fmaf(-2.f, (d0 + d1) + (d2 + d3), esq[c]);
            if (key < best) { best = key; bi = c; }   // c ascending -> first-min
        }
        sk[tid] = best; si[tid] = bi;
        __syncthreads();
        for (int s = 128; s > 0; s >>= 1) {
            if (tid < s) {
                float ok = sk[tid + s]; int oi = si[tid + s];
                if (ok < sk[tid] || (ok == sk[tid] && oi < si[tid])) { sk[tid] = ok; si[tid] = oi; }
            }
            __syncthreads();
        }
        if (tid == 0) idxf[row] = si[0];
        __syncthreads();
    }
}

// ---------------------------------------------------------------------------
// vq_gather: out_ind + out_q = embed[idx]. 8 threads per row.
// ---------------------------------------------------------------------------
__global__ __launch_bounds__(256) void vq_gather(const float* __restrict__ embed,
                                                 const int* __restrict__ idxf,
                                                 float* __restrict__ out_q,
                                                 float* __restrict__ out_ind) {
    int t = blockIdx.x * 256 + threadIdx.x;
    int r = t >> 3, q = t & 7;
    int c = idxf[r];
    const float4* src = (const float4*)(embed + (size_t)c * DIM + q * 8);
    float4* dst = (float4*)(out_q + (size_t)r * DIM + q * 8);
    dst[0] = src[0];
    dst[1] = src[1];
    if (q == 0) out_ind[r] = (float)c;
}

// ---------------------------------------------------------------------------
extern "C" void kernel_launch(void* const* d_in, const int* in_sizes, int n_in,
                              void* d_out, int out_size, void* d_ws, size_t ws_size,
                              hipStream_t stream) {
    const float* x = (const float*)d_in[0];      // [N, D] fp32
    const float* embed = (const float*)d_in[1];  // [1, K, D] fp32
    float* out = (float*)d_out;                  // [N*D quantize][N indices]

    char* ws = (char*)d_ws;
    short* e_pk = (short*)ws;                                    // 1 MB
    float* esq = (float*)(ws + (1 << 20));                       // 16 KB
    int* idxf = (int*)(ws + (1 << 20) + (16 << 10));             // 256 KB
    int* list = (int*)(ws + (1 << 20) + (16 << 10) + (256 << 10));  // 256 KB
    int* count = (int*)(ws + (1 << 20) + (16 << 10) + (512 << 10));

    pack_e<<<K_CODES / 32, 256, 0, stream>>>(embed, e_pk, esq, count);
    vq_main<<<N_ROWS / 128, 256, 0, stream>>>(x, e_pk, esq, idxf, list, count);
    vq_rescore<<<512, 256, 0, stream>>>(x, embed, esq, idxf, list, count);
    vq_gather<<<N_ROWS * 8 / 256, 256, 0, stream>>>(embed, idxf, out,
                                                    out + (size_t)N_ROWS * DIM);
}

// Round 5
// 161.446 us; speedup vs baseline: 3.8550x; 1.0657x over previous
//
#include <hip/hip_runtime.h>
#include <math.h>

#define N_ROWS 65536
#define K_CODES 4096
#define NTILES_TOTAL (K_CODES / 32)       // 128
#define K_CHUNKS 2
#define NTILES (NTILES_TOTAL / K_CHUNKS)  // 64 tiles per chunk
#define DIM 64
#define ACC_MARGIN 0.005f   // acc-space gap (= 0.01 in key space), ~16x error bound

typedef __attribute__((ext_vector_type(8))) short bf16x8;
typedef __attribute__((ext_vector_type(16))) float f32x16;

__device__ inline unsigned short f2bf_rne(float f) {
    unsigned u = __float_as_uint(f);
    return (unsigned short)((u + 0x7FFFu + ((u >> 16) & 1u)) >> 16);
}
__device__ inline float bf2f(unsigned short s) {
    return __uint_as_float(((unsigned)s) << 16);
}

// ---------------------------------------------------------------------------
// pack_e: hi/lo bf16 fragments (lane l elem j <- e[tile*32+(l&31)][ks*16+(l>>5)*8+j]),
// esq (for rescore), esqn = -esq/2 (MFMA C-init), count=0.
// ---------------------------------------------------------------------------
__global__ __launch_bounds__(256) void pack_e(const float* __restrict__ embed,
                                              short* __restrict__ e_pk,
                                              float* __restrict__ esq,
                                              float* __restrict__ esqn,
                                              int* __restrict__ count) {
    __shared__ float lds_f[2048];   // 32 codes x 64 dims
    const int tile = blockIdx.x;
    const int t = threadIdx.x;
    if (tile == 0 && t == 0) *count = 0;
    const float4* src = (const float4*)(embed + (size_t)tile * 2048);
    ((float4*)lds_f)[t] = src[t];
    ((float4*)lds_f)[t + 256] = src[t + 256];
    __syncthreads();
    const int l = t & 63, ks = t >> 6;
    const int base = (l & 31) * 64 + ks * 16 + (l >> 5) * 8;
    bf16x8 vh, vl;
#pragma unroll
    for (int j = 0; j < 8; ++j) {
        float v = lds_f[base + j];
        unsigned short h = f2bf_rne(v);
        vh[j] = (short)h;
        vl[j] = (short)f2bf_rne(v - bf2f(h));
    }
    *(bf16x8*)(e_pk + (size_t)tile * 4096 + t * 8) = vh;
    *(bf16x8*)(e_pk + (size_t)tile * 4096 + 2048 + t * 8) = vl;
    if (t < 32) {
        float s = 0.f;
#pragma unroll
        for (int d = 0; d < 64; ++d) { float v = lds_f[t * 64 + d]; s = fmaf(v, v, s); }
        esq[tile * 32 + t] = s;
        esqn[tile * 32 + t] = -0.5f * s;
    }
}

// ---------------------------------------------------------------------------
// vq_main: wave = 32 rows; block = 128 rows; each block covers ONE K-chunk
// (64 tiles). acc = x.e - e^2/2 via C-init; per-lane (max, second, idx);
// shfl merge; per-chunk results to ws.
// ---------------------------------------------------------------------------
__global__ __launch_bounds__(256, 4) void vq_main(const float* __restrict__ x,
                                                  const short* __restrict__ e_pk,
                                                  const float* __restrict__ esqn,
                                                  float* __restrict__ b1s,
                                                  float* __restrict__ b2s,
                                                  int* __restrict__ i1s) {
    __shared__ __align__(16) char lds[2][8192];   // dbuf: [hi 4KB][lo 4KB]
    const int tid = threadIdx.x;
    const int wid = tid >> 6;
    const int l = tid & 63;
    const int col = l & 31;
    const int g = l >> 5;
    const int kc = blockIdx.x & (K_CHUNKS - 1);
    const int rg = blockIdx.x >> 1;
    const int rowbase = rg * 128 + wid * 32;
    const int tile0 = kc * NTILES;

    // A fragments: on-the-fly hi/lo split of this lane's x row slice.
    const float* xrow = x + (size_t)(rowbase + col) * DIM;
    bf16x8 ah[4], al[4];
#pragma unroll
    for (int ks = 0; ks < 4; ++ks) {
        const float* p = xrow + ks * 16 + g * 8;
#pragma unroll
        for (int j = 0; j < 8; ++j) {
            float v = p[j];
            unsigned short h = f2bf_rne(v);
            ah[ks][j] = (short)h;
            al[ks][j] = (short)f2bf_rne(v - bf2f(h));
        }
    }

    float b1[16], b2[16];
    int i1[16];
#pragma unroll
    for (int i = 0; i < 16; ++i) { b1[i] = -3.0e38f; b2[i] = -3.0e38f; i1[i] = 0; }

    auto stage = [&](int t, int b) {
        const char* gsrc = (const char*)e_pk + (size_t)(tile0 + t) * 8192 + tid * 16;
        __builtin_amdgcn_global_load_lds(
            (const __attribute__((address_space(1))) void*)gsrc,
            (__attribute__((address_space(3))) void*)(&lds[b][wid * 1024]), 16, 0, 0);
        __builtin_amdgcn_global_load_lds(
            (const __attribute__((address_space(1))) void*)(gsrc + 4096),
            (__attribute__((address_space(3))) void*)(&lds[b][4096 + wid * 1024]), 16, 0, 0);
    };

    stage(0, 0);
    asm volatile("s_waitcnt vmcnt(0)" ::: "memory");
    __syncthreads();

    for (int t = 0; t < NTILES; ++t) {
        const int cur = t & 1;
        if (t + 1 < NTILES) stage(t + 1, cur ^ 1);   // prefetch overlaps compute
        const float esqn_v = esqn[(tile0 + t) * 32 + col];
        const int cidx = (tile0 + t) * 32 + col;

        f32x16 acc;
#pragma unroll
        for (int i = 0; i < 16; ++i) acc[i] = esqn_v;   // C-init = -e^2/2

#pragma unroll
        for (int ks = 0; ks < 4; ++ks) {
            const bf16x8 bh = *(const bf16x8*)(&lds[cur][(ks * 64 + l) * 16]);
            const bf16x8 bl = *(const bf16x8*)(&lds[cur][4096 + (ks * 64 + l) * 16]);
            acc = __builtin_amdgcn_mfma_f32_32x32x16_bf16(ah[ks], bh, acc, 0, 0, 0);
            acc = __builtin_amdgcn_mfma_f32_32x32x16_bf16(ah[ks], bl, acc, 0, 0, 0);
            acc = __builtin_amdgcn_mfma_f32_32x32x16_bf16(al[ks], bh, acc, 0, 0, 0);
        }

        // argmax tracking: 4 VALU per element.
#pragma unroll
        for (int i = 0; i < 16; ++i) {
            float val = acc[i];
            bool gt = val > b1[i];
            b2[i] = __builtin_amdgcn_fmed3f(val, b1[i], b2[i]);
            b1[i] = fmaxf(val, b1[i]);
            i1[i] = gt ? cidx : i1[i];
        }

        asm volatile("s_waitcnt vmcnt(0)" ::: "memory");
        __syncthreads();
    }

    // Cross-lane merge over the 32 cols (argmax; second = union formula).
#pragma unroll
    for (int i = 0; i < 16; ++i) {
#pragma unroll
        for (int m = 1; m <= 16; m <<= 1) {
            float ob1 = __shfl_xor(b1[i], m);
            float ob2 = __shfl_xor(b2[i], m);
            int oi = __shfl_xor(i1[i], m);
            float nb2 = fmaxf(fminf(b1[i], ob1), fmaxf(b2[i], ob2));
            bool take = ob1 > b1[i];
            b1[i] = take ? ob1 : b1[i];
            i1[i] = take ? oi : i1[i];
            b2[i] = nb2;
        }
        if (col == 0) {
            int row = rowbase + (i & 3) + 8 * (i >> 2) + 4 * g;  // m101 C/D row map
            b1s[(size_t)kc * N_ROWS + row] = b1[i];
            b2s[(size_t)kc * N_ROWS + row] = b2[i];
            i1s[(size_t)kc * N_ROWS + row] = i1[i];
        }
    }
}

// ---------------------------------------------------------------------------
// vq_merge_gather: merge the 2 chunks per row, flag close calls, write
// out_ind + out_q (8 threads per row).
// ---------------------------------------------------------------------------
__global__ __launch_bounds__(256) void vq_merge_gather(const float* __restrict__ embed,
                                                       const float* __restrict__ b1s,
                                                       const float* __restrict__ b2s,
                                                       const int* __restrict__ i1s,
                                                       float* __restrict__ out_q,
                                                       float* __restrict__ out_ind,
                                                       int* __restrict__ list,
                                                       int* __restrict__ count) {
    int t = blockIdx.x * 256 + threadIdx.x;
    int r = t >> 3, q = t & 7;
    float ab1 = b1s[r], bb1 = b1s[N_ROWS + r];
    float ab2 = b2s[r], bb2 = b2s[N_ROWS + r];
    int ai = i1s[r], bi = i1s[N_ROWS + r];
    bool take = bb1 > ab1;                 // tie -> chunk 0 (lower index); ties flagged anyway
    int idx = take ? bi : ai;
    float m1 = fmaxf(ab1, bb1);
    float m2 = fmaxf(fminf(ab1, bb1), fmaxf(ab2, bb2));
    const float4* src = (const float4*)(embed + (size_t)idx * DIM + q * 8);
    float4* dst = (float4*)(out_q + (size_t)r * DIM + q * 8);
    dst[0] = src[0];
    dst[1] = src[1];
    if (q == 0) {
        out_ind[r] = (float)idx;
        if (m1 - m2 < ACC_MARGIN) {
            int p = atomicAdd(count, 1);
            list[p] = r;
        }
    }
}

// ---------------------------------------------------------------------------
// vq_rescore: exact fp32 full rescan of flagged rows; patches out directly.
// ---------------------------------------------------------------------------
__global__ __launch_bounds__(256) void vq_rescore(const float* __restrict__ x,
                                                  const float* __restrict__ embed,
                                                  const float* __restrict__ esq,
                                                  const int* __restrict__ list,
                                                  const int* __restrict__ count,
                                                  float* __restrict__ out_q,
                                                  float* __restrict__ out_ind) {
    __shared__ float xs[64];
    __shared__ float sk[256];
    __shared__ int si[256];
    const int tid = threadIdx.x;
    const int n = *count;
    for (int f = blockIdx.x; f < n; f += gridDim.x) {
        const int row = list[f];
        if (tid < 16) ((float4*)xs)[tid] = ((const float4*)(x + (size_t)row * DIM))[tid];
        __syncthreads();
        float best = 3.0e38f;
        int bi = 0;
        for (int i = 0; i < 16; ++i) {
            int c = tid + (i << 8);
            const float* e = embed + (size_t)c * DIM;
            float d0 = 0, d1 = 0, d2 = 0, d3 = 0;
#pragma unroll
            for (int d = 0; d < 64; d += 4) {
                d0 = fmaf(xs[d + 0], e[d + 0], d0);
                d1 = fmaf(xs[d + 1], e[d + 1], d1);
                d2 = fmaf(xs[d + 2], e[d + 2], d2);
                d3 = fmaf(xs[d + 3], e[d + 3], d3);
            }
            float key = fmaf(-2.f, (d0 + d1) + (d2 + d3), esq[c]);
            if (key < best) { best = key; bi = c; }   // c ascending -> first-min
        }
        sk[tid] = best; si[tid] = bi;
        __syncthreads();
        for (int s = 128; s > 0; s >>= 1) {
            if (tid < s) {
                float ok = sk[tid + s]; int oi = si[tid + s];
                if (ok < sk[tid] || (ok == sk[tid] && oi < si[tid])) { sk[tid] = ok; si[tid] = oi; }
            }
            __syncthreads();
        }
        if (tid == 0) out_ind[row] = (float)si[0];
        if (tid < 16) {
            const float4* src = (const float4*)(embed + (size_t)si[0] * DIM);
            ((float4*)(out_q + (size_t)row * DIM))[tid] = src[tid];
        }
        __syncthreads();
    }
}

// ---------------------------------------------------------------------------
extern "C" void kernel_launch(void* const* d_in, const int* in_sizes, int n_in,
                              void* d_out, int out_size, void* d_ws, size_t ws_size,
                              hipStream_t stream) {
    const float* x = (const float*)d_in[0];      // [N, D] fp32
    const float* embed = (const float*)d_in[1];  // [1, K, D] fp32
    float* out = (float*)d_out;                  // [N*D quantize][N indices]
    float* out_ind = out + (size_t)N_ROWS * DIM;

    char* ws = (char*)d_ws;
    short* e_pk = (short*)ws;                            // 1 MB
    size_t off = 1 << 20;
    float* esq = (float*)(ws + off);  off += 16 << 10;   // 16 KB
    float* esqn = (float*)(ws + off); off += 16 << 10;   // 16 KB
    float* b1s = (float*)(ws + off);  off += (size_t)K_CHUNKS * N_ROWS * 4;
    float* b2s = (float*)(ws + off);  off += (size_t)K_CHUNKS * N_ROWS * 4;
    int* i1s = (int*)(ws + off);      off += (size_t)K_CHUNKS * N_ROWS * 4;
    int* list = (int*)(ws + off);     off += (size_t)N_ROWS * 4;
    int* count = (int*)(ws + off);

    pack_e<<<NTILES_TOTAL, 256, 0, stream>>>(embed, e_pk, esq, esqn, count);
    vq_main<<<(N_ROWS / 128) * K_CHUNKS, 256, 0, stream>>>(x, e_pk, esqn, b1s, b2s, i1s);
    vq_merge_gather<<<N_ROWS * 8 / 256, 256, 0, stream>>>(embed, b1s, b2s, i1s,
                                                          out, out_ind, list, count);
    vq_rescore<<<512, 256, 0, stream>>>(x, embed, esq, list, count, out, out_ind);
}